// Round 3
// baseline (233.296 us; speedup 1.0000x reference)
//
#include <hip/hip_runtime.h>

#define NB    256    // bins per batch (== TPB, thread<->bin in dir 2)
#define BPB   512    // blocks per batch -> 2048 blocks = 8/CU exactly
#define TPB   256
#define CHMAX 320    // chunk = ceil(157696/512) = 308, padded for float4
#define SENTF 1e18f  // sentinel: d^2 ~ 1e36, finite, loses every min

__global__ __launch_bounds__(TPB, 8) void chamfer_fused(
    const float* __restrict__ bc, const float* __restrict__ gt,
    int B, int V, int CH,
    float* __restrict__ sumA_part, int* __restrict__ cnt_part,
    unsigned* __restrict__ binmin, unsigned* __restrict__ counter,
    float* __restrict__ out)
{
    const int b   = blockIdx.x / BPB;
    const int blk = blockIdx.x % BPB;
    const int tid = threadIdx.x;
    const int start = blk * CH;
    const int cn  = min(CH, V - start);
    const int cn4 = (cn + 3) >> 2;

    __shared__ float s_c[NB];      // bin centers
    __shared__ float s_p[CHMAX];   // sanitized points
    __shared__ float rs[4];
    __shared__ float rm[4];
    __shared__ int   ri[4];
    __shared__ int   sn[8];
    __shared__ float ssa[8];
    __shared__ unsigned s_last;

    s_c[tid] = bc[b * NB + tid];   // NB == TPB

    // stage + sanitize points (validity folded in ONCE; hot loops are 3 ops/dist)
    const float* __restrict__ gp = gt + (size_t)b * V + start;
    int cnt = 0;
    for (int i = tid; i < cn; i += TPB) {
        float v = gp[i];
        bool ok = (v >= 0.001f);
        cnt += ok ? 1 : 0;
        s_p[i] = ok ? v : SENTF;
    }
    for (int i = cn + tid; i < CHMAX; i += TPB) s_p[i] = SENTF;  // pad for float4 reads
    __syncthreads();

    // ---- dir 1: each point -> nearest bin (ds_read_b128 broadcast over bins) ----
    float sum = 0.f;
    const float4* __restrict__ c4p = (const float4*)s_c;
    for (int i = tid; i < cn; i += TPB) {
        float p = s_p[i];               // stride-1 across lanes: 2-way, free
        float m0 = 1e30f, m1 = 1e30f, m2 = 1e30f, m3 = 1e30f;
        #pragma unroll 4
        for (int j = 0; j < NB / 4; ++j) {
            float4 c4 = c4p[j];         // wave-uniform -> LDS broadcast, free
            float d0 = c4.x - p; m0 = fminf(m0, d0 * d0);
            float d1 = c4.y - p; m1 = fminf(m1, d1 * d1);
            float d2 = c4.z - p; m2 = fminf(m2, d2 * d2);
            float d3 = c4.w - p; m3 = fminf(m3, d3 * d3);
        }
        float dm = fminf(fminf(m0, m1), fminf(m2, m3));
        sum += (p < 1e17f) ? dm : 0.f;  // sentinel points excluded
    }

    // ---- dir 2: bin `tid` -> nearest point (ds_read_b128 broadcast over points) ----
    const float c = s_c[tid];
    float n0 = 1e30f, n1 = 1e30f, n2 = 1e30f, n3 = 1e30f;
    const float4* __restrict__ p4 = (const float4*)s_p;
    #pragma unroll 4
    for (int i = 0; i < cn4; ++i) {
        float4 q = p4[i];               // wave-uniform -> LDS broadcast, free
        float d0 = c - q.x; n0 = fminf(n0, d0 * d0);
        float d1 = c - q.y; n1 = fminf(n1, d1 * d1);
        float d2 = c - q.z; n2 = fminf(n2, d2 * d2);
        float d3 = c - q.w; n3 = fminf(n3, d3 * d3);
    }
    float m = fminf(fminf(n0, n1), fminf(n2, n3));
    // nonneg float ordering == uint ordering; exact min -> deterministic
    atomicMin(&binmin[b * NB + tid], __float_as_uint(m));

    // ---- block reduce dir-1 sum + valid count (shuffle, deterministic) ----
    for (int off = 32; off; off >>= 1) {
        sum += __shfl_down(sum, off);
        cnt += __shfl_down(cnt, off);
    }
    if ((tid & 63) == 0) { rs[tid >> 6] = sum; ri[tid >> 6] = cnt; }
    __syncthreads();
    if (tid == 0) {
        sumA_part[b * BPB + blk] = rs[0] + rs[1] + rs[2] + rs[3];
        cnt_part [b * BPB + blk] = ri[0] + ri[1] + ri[2] + ri[3];
    }

    // ---- last-block-done finalize (counter starts at 0xFFFFFFFF from the 0xFF memset,
    //      so old values run 0xFFFFFFFF, 0, 1, ..., gridDim-2; last sees gridDim-2) ----
    __threadfence();
    if (tid == 0) s_last = atomicAdd(counter, 1u);
    __syncthreads();
    if (s_last != (unsigned)(gridDim.x - 2)) return;
    __threadfence();

    // per-batch n and sumA
    for (int bb = 0; bb < B; ++bb) {
        float s = 0.f; int cc = 0;
        for (int i = tid; i < BPB; i += TPB) {
            s  += sumA_part[bb * BPB + i];
            cc += cnt_part [bb * BPB + i];
        }
        for (int off = 32; off; off >>= 1) {
            s  += __shfl_down(s, off);
            cc += __shfl_down(cc, off);
        }
        if ((tid & 63) == 0) { rs[tid >> 6] = s; ri[tid >> 6] = cc; }
        __syncthreads();
        if (tid == 0) {
            ssa[bb] = rs[0] + rs[1] + rs[2] + rs[3];
            sn[bb]  = ri[0] + ri[1] + ri[2] + ri[3];
        }
        __syncthreads();
    }

    int Lmax = 0;
    for (int bb = 0; bb < B; ++bb) Lmax = max(Lmax, sn[bb]);

    float total = 0.f;
    for (int bb = 0; bb < B; ++bb) {
        const int   npad = Lmax - sn[bb];
        const float cc   = bc[bb * NB + tid];
        const float cc2  = cc * cc;
        float bm = __uint_as_float(binmin[bb * NB + tid]);
        if (npad > 0) bm = fminf(bm, cc2);  // pad points sit at 0 -> dist c^2
        float s = bm, mc = cc2;
        for (int off = 32; off; off >>= 1) {
            s  += __shfl_down(s, off);
            float o = __shfl_down(mc, off);
            mc = fminf(mc, o);
        }
        if ((tid & 63) == 0) { rs[tid >> 6] = s; rm[tid >> 6] = mc; }
        __syncthreads();
        if (tid == 0) {
            float sb = rs[0] + rs[1] + rs[2] + rs[3];
            float mn = fminf(fminf(rm[0], rm[1]), fminf(rm[2], rm[3]));
            total += ssa[bb] + (float)npad * mn + sb;
        }
        __syncthreads();
    }
    if (tid == 0) out[0] = total / (float)B;   // batch_reduction = mean
}

extern "C" void kernel_launch(void* const* d_in, const int* in_sizes, int n_in,
                              void* d_out, int out_size, void* d_ws, size_t ws_size,
                              hipStream_t stream) {
    const float* bc = (const float*)d_in[0];   // [B, 256, 1]
    const float* gt = (const float*)d_in[1];   // [B, 1, H, W]
    const int B  = in_sizes[0] / NB;           // 4
    const int V  = in_sizes[1] / B;            // 157696
    const int CH = (V + BPB - 1) / BPB;        // 308 (= 4*77, <= CHMAX)

    float*    sumA_part = (float*)d_ws;
    int*      cnt_part  = (int*)(sumA_part + B * BPB);
    unsigned* binmin    = (unsigned*)(cnt_part + B * BPB);
    unsigned* counter   = binmin + B * NB;

    // ONE memset covers binmin (identity for uint atomicMin on nonneg float bits)
    // AND the completion counter (starts at 0xFFFFFFFF; kernel accounts for it).
    hipMemsetAsync(binmin, 0xFF, ((size_t)B * NB + 1) * sizeof(unsigned), stream);

    chamfer_fused<<<B * BPB, TPB, 0, stream>>>(
        bc, gt, B, V, CH, sumA_part, cnt_part, binmin, counter, (float*)d_out);
}

// Round 4
// 100.116 us; speedup vs baseline: 2.3303x; 2.3303x over previous
//
#include <hip/hip_runtime.h>

#define NB    256    // bins per batch (== TPB; thread<->bin in dir 2 / finalize)
#define TPB   256
#define SENTP 1e18f  // sentinel point: d^2 ~ 1e36, finite, loses every min
#define MINF  1e30f

// ---------------- kernel 1: per-chunk partials (no atomics, no fences) -------
__global__ __launch_bounds__(TPB) void chamfer_part(
    const float* __restrict__ bc, const float* __restrict__ gt,
    int B, int V, int BPB, int CH,
    float* __restrict__ sumA_part, int* __restrict__ cnt_part,
    float* __restrict__ binpart)
{
    const int b   = blockIdx.x / BPB;
    const int blk = blockIdx.x - b * BPB;
    const int tid = threadIdx.x;
    const int start = blk * CH;
    const int cn  = min(CH, V - start);

    const float* __restrict__ cb = bc + (size_t)b * NB;
    const float* __restrict__ gp = gt + (size_t)b * V + start;

    // ---- direction 1: thread-owned points vs uniform-streamed bins ----
    // bins are wave-uniform -> s_load batches on the SMEM pipe (no LDS, no
    // per-lane delivery); points live in VGPRs. 3 VALU ops per pair.
    float sum = 0.f; int cnt = 0;
    for (int base = 0; base < cn; base += 2 * TPB) {
        const int ia = base + tid, ib = base + TPB + tid;
        float pa = SENTP, pb = SENTP; bool va = false, vb = false;
        if (ia < cn) { float v = gp[ia]; va = (v >= 0.001f); pa = va ? v : SENTP; }
        if (ib < cn) { float v = gp[ib]; vb = (v >= 0.001f); pb = vb ? v : SENTP; }
        cnt += (va ? 1 : 0) + (vb ? 1 : 0);
        float ma = MINF, mb = MINF;
        for (int j0 = 0; j0 < NB; j0 += 8) {
            #pragma unroll
            for (int jj = 0; jj < 8; ++jj) {
                const float cj = cb[j0 + jj];          // uniform -> SGPR
                float da = cj - pa; ma = fminf(ma, da * da);
                float db = cj - pb; mb = fminf(mb, db * db);
            }
        }
        sum += (va ? ma : 0.f) + (vb ? mb : 0.f);
    }

    // ---- direction 2: thread-owned bin vs uniform-streamed points ----
    const float c = cb[tid];                           // per-lane (NB == TPB)
    float m0 = MINF, m1 = MINF, m2 = MINF, m3 = MINF;
    int i = 0;
    for (; i + 8 <= cn; i += 8) {
        #pragma unroll
        for (int jj = 0; jj < 8; ++jj) {
            float q = gp[i + jj];                      // uniform -> s_load batch
            q = (q >= 0.001f) ? q : SENTP;             // uniform -> scalar select
            const float d = c - q;
            if ((jj & 3) == 0)      m0 = fminf(m0, d * d);
            else if ((jj & 3) == 1) m1 = fminf(m1, d * d);
            else if ((jj & 3) == 2) m2 = fminf(m2, d * d);
            else                    m3 = fminf(m3, d * d);
        }
    }
    for (; i < cn; ++i) {
        float q = gp[i];
        q = (q >= 0.001f) ? q : SENTP;
        const float d = c - q;
        m0 = fminf(m0, d * d);
    }
    // coalesced plain store of this chunk's per-bin minima (no atomicMin)
    binpart[(size_t)blockIdx.x * NB + tid] = fminf(fminf(m0, m1), fminf(m2, m3));

    // ---- deterministic block reduce of dir-1 sum + valid count ----
    for (int off = 32; off; off >>= 1) {
        sum += __shfl_down(sum, off);
        cnt += __shfl_down(cnt, off);
    }
    __shared__ float r4[4]; __shared__ int i4[4];
    if ((tid & 63) == 0) { r4[tid >> 6] = sum; i4[tid >> 6] = cnt; }
    __syncthreads();
    if (tid == 0) {
        sumA_part[blockIdx.x] = r4[0] + r4[1] + r4[2] + r4[3];
        cnt_part [blockIdx.x] = i4[0] + i4[1] + i4[2] + i4[3];
    }
}

// ------------- kernel 2: reduce per-chunk bin minima (16 blocks) -------------
__global__ __launch_bounds__(TPB) void chamfer_binred(
    const float* __restrict__ binpart, float* __restrict__ binmin2, int BPB)
{
    const int b = blockIdx.x >> 2, quarter = blockIdx.x & 3;
    const int lane = threadIdx.x & 63, slice = threadIdx.x >> 6;
    const int bin = quarter * 64 + lane;
    const int per = (BPB + 3) >> 2;
    const int c0 = slice * per, c1 = min(BPB, c0 + per);

    const float* __restrict__ base = binpart + (size_t)b * BPB * NB + bin;
    float m = MINF;
    #pragma unroll 4
    for (int ch = c0; ch < c1; ++ch)
        m = fminf(m, base[(size_t)ch * NB]);   // 64 consecutive dwords per wave

    __shared__ float sm[4][64];
    sm[slice][lane] = m;
    __syncthreads();
    if (slice == 0)
        binmin2[b * NB + bin] =
            fminf(fminf(sm[0][lane], sm[1][lane]), fminf(sm[2][lane], sm[3][lane]));
}

// ------------- kernel 3: finalize (1 block, deterministic) -------------------
__global__ __launch_bounds__(TPB) void chamfer_final(
    const float* __restrict__ bc,
    const float* __restrict__ sumA_part, const int* __restrict__ cnt_part,
    const float* __restrict__ binmin2,
    int B, int BPB, float* __restrict__ out)
{
    const int tid = threadIdx.x;
    __shared__ float r4[4]; __shared__ int i4[4]; __shared__ float q4[4];
    __shared__ float ssa[8]; __shared__ int sn[8];

    // per-batch valid count n and dir-1 sum
    for (int bb = 0; bb < B; ++bb) {
        float s = 0.f; int cc = 0;
        for (int k = tid; k < BPB; k += TPB) {
            s  += sumA_part[bb * BPB + k];
            cc += cnt_part [bb * BPB + k];
        }
        for (int off = 32; off; off >>= 1) {
            s += __shfl_down(s, off); cc += __shfl_down(cc, off);
        }
        if ((tid & 63) == 0) { r4[tid >> 6] = s; i4[tid >> 6] = cc; }
        __syncthreads();
        if (tid == 0) {
            ssa[bb] = r4[0] + r4[1] + r4[2] + r4[3];
            sn[bb]  = i4[0] + i4[1] + i4[2] + i4[3];
        }
        __syncthreads();
    }

    int Lmax = 0;
    for (int bb = 0; bb < B; ++bb) Lmax = max(Lmax, sn[bb]);

    float total = 0.f;
    for (int bb = 0; bb < B; ++bb) {
        const int   npad = Lmax - sn[bb];
        const float cc   = bc[bb * NB + tid];
        const float c2   = cc * cc;
        float bm = binmin2[bb * NB + tid];
        if (npad > 0) bm = fminf(bm, c2);    // pad points sit at 0 -> dist c^2
        float s = bm, mc = c2;
        for (int off = 32; off; off >>= 1) {
            s  += __shfl_down(s, off);
            mc  = fminf(mc, __shfl_down(mc, off));
        }
        if ((tid & 63) == 0) { r4[tid >> 6] = s; q4[tid >> 6] = mc; }
        __syncthreads();
        if (tid == 0)
            total += ssa[bb]
                   + (float)npad * fminf(fminf(q4[0], q4[1]), fminf(q4[2], q4[3]))
                   + (r4[0] + r4[1] + r4[2] + r4[3]);
        __syncthreads();
    }
    if (tid == 0) out[0] = total / (float)B;   // batch_reduction = mean
}

extern "C" void kernel_launch(void* const* d_in, const int* in_sizes, int n_in,
                              void* d_out, int out_size, void* d_ws, size_t ws_size,
                              hipStream_t stream) {
    const float* bc = (const float*)d_in[0];   // [B, 256, 1]
    const float* gt = (const float*)d_in[1];   // [B, 1, H, W]
    const int B = in_sizes[0] / NB;            // 4
    const int V = in_sizes[1] / B;             // 157696 = 2^11 * 7 * 11

    // largest chunk count whose workspace fits (BPB=308 -> CH=512 = 2 pts/thread)
    const int cand[] = {308, 154, 77, 44, 28, 14, 8, 4, 2, 1};
    int BPB = 1;
    for (int k = 0; k < 10; ++k) {
        size_t need = (size_t)B * cand[k] * NB * 4   // binpart
                    + (size_t)B * cand[k] * 8        // sumA_part + cnt_part
                    + (size_t)B * NB * 4 + 64;       // binmin2
        if (need <= ws_size) { BPB = cand[k]; break; }
    }
    const int CH = (V + BPB - 1) / BPB;

    float* binpart   = (float*)d_ws;                          // [B*BPB, NB]
    float* sumA_part = binpart + (size_t)B * BPB * NB;        // [B*BPB]
    int*   cnt_part  = (int*)(sumA_part + (size_t)B * BPB);   // [B*BPB]
    float* binmin2   = (float*)(cnt_part + (size_t)B * BPB);  // [B, NB]

    chamfer_part<<<B * BPB, TPB, 0, stream>>>(bc, gt, B, V, BPB, CH,
                                              sumA_part, cnt_part, binpart);
    chamfer_binred<<<B * 4, TPB, 0, stream>>>(binpart, binmin2, BPB);
    chamfer_final<<<1, TPB, 0, stream>>>(bc, sumA_part, cnt_part, binmin2,
                                         B, BPB, (float*)d_out);
}